// Round 16
// baseline (315.899 us; speedup 1.0000x reference)
//
#include <hip/hip_runtime.h>

// Decoder via MFMA implicit GEMM, mixed-precision:
//   L0: bf16 hi/lo x bf16 hi/lo (3-term). L1-L5: fp16-single activations x fp16 hi/lo
//   weights (2-term). R14/R15 measured: fp16 internal edges add ZERO absmax error.
// conv_transpose SAME:
//   stride1: O[o] = sum_k W[k] X[o+k-1]
//   stride2, parity r: r==1 -> tap kd=1,id=i ; r==0 -> kd=2,id=i and kd=0,id=i-1  (o=2i+r)
// Weights DHWIO [tap][ci][co], activations NDHWC.
// MFMA layouts (verified): A[m=lane&15][k=(lane>>4)*8+j], B[n=lane&15][k=(lane>>4)*8+j],
// D: col=lane&15, row=(lane>>4)*4+reg. C/D layout dtype-independent.
// LDS rule (R10): voxel slot stride must be a multiple of 8 u16 (16B) or b128 ops split.
//
// Round16: halve barrier phases in the two LDS kernels — fp16 lets a 72-u16 slot hold
// TWO kc slices (64 fp16 + 8 pad). L3: 4 staging phases -> 2; L5: 6 -> 3. Per-tap MFMA
// doubles against the same barrier count (R15 showed staging/barrier fraction grew when
// MFMA work shrank: MfmaUtil 42->36.5). Everything else identical to R15.

typedef __attribute__((ext_vector_type(8))) short bf16x8;
typedef __attribute__((ext_vector_type(8))) _Float16 f16x8;
typedef __attribute__((ext_vector_type(4))) float f32x4;
typedef unsigned short u16;

__device__ __forceinline__ u16 f2bf(float f) {
    unsigned u = __builtin_bit_cast(unsigned, f);
    u += 0x7fffu + ((u >> 16) & 1u);
    return (u16)(u >> 16);
}
__device__ __forceinline__ float bf2f(u16 h) {
    unsigned u = ((unsigned)h) << 16;
    return __builtin_bit_cast(float, u);
}
__device__ __forceinline__ void split_store(float v, u16* ph, u16* pl) {
    u16 h = f2bf(v);
    *ph = h;
    *pl = f2bf(v - bf2f(h));
}
__device__ __forceinline__ u16 f2h(float v) {
    return __builtin_bit_cast(u16, (_Float16)v);
}
__device__ __forceinline__ int swz(int bx, int G) { return (bx & 7) * (G >> 3) + (bx >> 3); }

// pack fp32 w[27][Cin][Cout] -> frags [tap][nt][kc][lane][8].
// Layer 0: bf16 hi/lo. Layers 1-5: fp16 hi/lo. y==6: split x bf16 hi/lo + zero page.
__global__ __launch_bounds__(256) void pack_all(
    const float* __restrict__ x, float* __restrict__ zf,
    u16* __restrict__ Xh, u16* __restrict__ Xl,
    const float* __restrict__ w0_, const float* __restrict__ w1_,
    const float* __restrict__ w2_, const float* __restrict__ w3_,
    const float* __restrict__ w4_, const float* __restrict__ w5_,
    u16* s0h, u16* s0l, u16* s1h, u16* s1l, u16* s2h, u16* s2l,
    u16* s3h, u16* s3l, u16* s4h, u16* s4l, u16* s5h, u16* s5l)
{
    if (blockIdx.y == 6) {
        if (blockIdx.x < 64) {
            const int i = (blockIdx.x * 256 + threadIdx.x) * 4;
            const float4 v = *(const float4*)(x + i);
            split_store(v.x, Xh + i,     Xl + i);
            split_store(v.y, Xh + i + 1, Xl + i + 1);
            split_store(v.z, Xh + i + 2, Xl + i + 2);
            split_store(v.w, Xh + i + 3, Xl + i + 3);
        } else if (blockIdx.x == 64) {
            ((float4*)zf)[threadIdx.x] = make_float4(0.f, 0.f, 0.f, 0.f);
        }
        return;
    }
    const float* w; u16 *bh, *bl; int Cin, Cout, nNt;
    switch (blockIdx.y) {
        case 0: w = w0_; bh = s0h; bl = s0l; Cin = 128; Cout = 128; nNt = 8; break;
        case 1: w = w1_; bh = s1h; bl = s1l; Cin = 128; Cout = 128; nNt = 8; break;
        case 2: w = w2_; bh = s2h; bl = s2l; Cin = 128; Cout = 128; nNt = 8; break;
        case 3: w = w3_; bh = s3h; bl = s3l; Cin = 128; Cout = 128; nNt = 8; break;
        case 4: w = w4_; bh = s4h; bl = s4l; Cin = 128; Cout = 64;  nNt = 4; break;
        default:w = w5_; bh = s5h; bl = s5l; Cin = 64;  Cout = 3;   nNt = 1; break;
    }
    const bool f16 = (blockIdx.y >= 1);
    const int KC = Cin >> 5;
    const int total = 27 * nNt * KC * 64;
    int t = blockIdx.x * 256 + threadIdx.x;
    if (t >= total) return;
    const int lane = t & 63;
    int r = t >> 6;
    const int kc = r % KC; r /= KC;
    const int nt = r % nNt; r /= nNt;
    const int tap = r;
    const int n  = nt * 16 + (lane & 15);
    const int k0 = kc * 32 + (lane >> 4) * 8;
    const size_t o = (size_t)t * 8;
    for (int j = 0; j < 8; ++j) {
        float v = (n < Cout) ? w[((size_t)tap * Cin + k0 + j) * Cout + n] : 0.f;
        if (f16) {
            const _Float16 h = (_Float16)v;
            bh[o + j] = __builtin_bit_cast(u16, h);
            bl[o + j] = f2h(v - (float)h);
        } else {
            const u16 h = f2bf(v);
            bh[o + j] = h;
            bl[o + j] = f2bf(v - bf2f(h));
        }
    }
}

// ---------- L0 only: stride-2 bf16 hi/lo 3-term, fp16-single output ----------
template<int CIN, int MT, int NT>
__global__ __launch_bounds__(64) void deconv_s2_bf16(
    const u16* __restrict__ Ah, const u16* __restrict__ Al,
    const u16* __restrict__ Bh, const u16* __restrict__ Bl,
    const float* __restrict__ bias, const u16* __restrict__ Z,
    u16* __restrict__ Y, int Din, int lD, int Cout, int nNtTot)
{
    constexpr int KC = CIN >> 5;
    const int Dout = 2 * Din;
    const int lane = threadIdx.x;
    const int ml = lane & 15, kq = lane >> 4;
    const int M0 = swz(blockIdx.x, gridDim.x) * (MT * 16);
    const int N0t = blockIdx.y * NT;
    const int par = blockIdx.z;
    const int rd = (par >> 2) & 1, rh = (par >> 1) & 1, rw = par & 1;

    int sw[MT], sh[MT], sd[MT];
    #pragma unroll
    for (int mt = 0; mt < MT; ++mt) {
        const int sv = M0 + mt * 16 + ml;
        sw[mt] = sv & (Din - 1); sh[mt] = (sv >> lD) & (Din - 1); sd[mt] = sv >> (2 * lD);
    }

    f32x4 acc[MT][NT];
    #pragma unroll
    for (int nt = 0; nt < NT; ++nt) {
        const float bv = bias[(N0t + nt) * 16 + ml];
        #pragma unroll
        for (int mt = 0; mt < MT; ++mt) acc[mt][nt] = (f32x4){bv, bv, bv, bv};
    }

    const int lw = rw ? 0 : 1, lh = rh ? 0 : 1, ld2 = rd ? 0 : 1;
    const int ntap = 1 << (lw + lh + ld2);

    const u16 *pah[MT], *pal[MT];
    size_t fb;
    auto set_tap = [&](int t) {
        const int tw_ = t & ((1 << lw) - 1);
        const int th_ = (t >> lw) & ((1 << lh) - 1);
        const int td_ = t >> (lw + lh);
        const int kd = rd ? 1 : (td_ ? 0 : 2);
        const int kh = rh ? 1 : (th_ ? 0 : 2);
        const int kw = rw ? 1 : (tw_ ? 0 : 2);
        const int dd = rd ? 0 : -td_, dh = rh ? 0 : -th_, dw = rw ? 0 : -tw_;
        const int tap = (kd * 3 + kh) * 3 + kw;
        #pragma unroll
        for (int mt = 0; mt < MT; ++mt) {
            const int id = sd[mt] + dd, ih = sh[mt] + dh, iw = sw[mt] + dw;
            const bool v = id >= 0 && ih >= 0 && iw >= 0;
            const size_t off = (size_t)((id * Din + ih) * Din + iw) * CIN;
            pah[mt] = v ? Ah + off : Z;
            pal[mt] = v ? Al + off : Z;
        }
        fb = ((size_t)tap * nNtTot + N0t) * KC;
    };

    bf16x8 fah[2][MT], fal[2][MT], fbh[2][NT], fbl[2][NT];
    auto load_frags = [&](int buf, int kc) {
        const int ko = kc * 32 + kq * 8;
        #pragma unroll
        for (int mt = 0; mt < MT; ++mt) {
            fah[buf][mt] = *(const bf16x8*)(pah[mt] + ko);
            fal[buf][mt] = *(const bf16x8*)(pal[mt] + ko);
        }
        #pragma unroll
        for (int nt = 0; nt < NT; ++nt) {
            const size_t fo = (fb + (size_t)nt * KC + kc) * 512 + lane * 8;
            fbh[buf][nt] = *(const bf16x8*)(Bh + fo);
            fbl[buf][nt] = *(const bf16x8*)(Bl + fo);
        }
    };

    set_tap(0);
    load_frags(0, 0);

    for (int t = 0; t < ntap; ++t) {
        #pragma unroll
        for (int kc = 0; kc < KC; ++kc) {
            const int cur = kc & 1, nxt = cur ^ 1;
            if (kc + 1 < KC) {
                load_frags(nxt, kc + 1);
            } else {
                set_tap(t + 1 < ntap ? t + 1 : t);
                load_frags(nxt, 0);
            }
            #pragma unroll
            for (int mt = 0; mt < MT; ++mt)
            #pragma unroll
            for (int nt = 0; nt < NT; ++nt) {
                acc[mt][nt] = __builtin_amdgcn_mfma_f32_16x16x32_bf16(fah[cur][mt], fbh[cur][nt], acc[mt][nt], 0, 0, 0);
                acc[mt][nt] = __builtin_amdgcn_mfma_f32_16x16x32_bf16(fah[cur][mt], fbl[cur][nt], acc[mt][nt], 0, 0, 0);
                acc[mt][nt] = __builtin_amdgcn_mfma_f32_16x16x32_bf16(fal[cur][mt], fbh[cur][nt], acc[mt][nt], 0, 0, 0);
            }
        }
    }

    #pragma unroll
    for (int mt = 0; mt < MT; ++mt) {
        #pragma unroll
        for (int r = 0; r < 4; ++r) {
            const int sv = M0 + mt * 16 + kq * 4 + r;
            const int svw = sv & (Din - 1), svh = (sv >> lD) & (Din - 1), svd = sv >> (2 * lD);
            const int od = 2 * svd + rd, oh = 2 * svh + rh, ow = 2 * svw + rw;
            const size_t yb = (size_t)((od * Dout + oh) * Dout + ow) * Cout;
            #pragma unroll
            for (int nt = 0; nt < NT; ++nt)
                Y[yb + (N0t + nt) * 16 + ml] = f2h(acc[mt][nt][r]);
        }
    }
}

// ---------- fp16 stride-1 conv: A single, W hi/lo, 2-term; fp16-single out ----------
template<int CIN, int MT, int NT, bool RELU>
__global__ __launch_bounds__(64) void conv_s1_f16(
    const u16* __restrict__ A, const u16* __restrict__ Bh, const u16* __restrict__ Bl,
    const float* __restrict__ bias, const u16* __restrict__ Z,
    u16* __restrict__ Y, int D, int lD, int Cout, int nNtTot)
{
    constexpr int KC = CIN >> 5;
    const int lane = threadIdx.x;
    const int ml = lane & 15, kq = lane >> 4;
    const int M0 = swz(blockIdx.x, gridDim.x) * (MT * 16);
    const int N0t = blockIdx.y * NT;

    int vw[MT], vh[MT], vd[MT];
    #pragma unroll
    for (int mt = 0; mt < MT; ++mt) {
        const int vox = M0 + mt * 16 + ml;
        vw[mt] = vox & (D - 1); vh[mt] = (vox >> lD) & (D - 1); vd[mt] = vox >> (2 * lD);
    }

    f32x4 acc[MT][NT];
    #pragma unroll
    for (int nt = 0; nt < NT; ++nt) {
        const float bv = bias[(N0t + nt) * 16 + ml];
        #pragma unroll
        for (int mt = 0; mt < MT; ++mt) acc[mt][nt] = (f32x4){bv, bv, bv, bv};
    }

    const u16* pa[MT];
    size_t fb;
    auto set_tap = [&](int tap) {
        const int kd = tap / 9, kh = (tap % 9) / 3, kw = tap % 3;
        #pragma unroll
        for (int mt = 0; mt < MT; ++mt) {
            const int id = vd[mt] + kd - 1, ih = vh[mt] + kh - 1, iw = vw[mt] + kw - 1;
            const bool v = (unsigned)id < (unsigned)D && (unsigned)ih < (unsigned)D &&
                           (unsigned)iw < (unsigned)D;
            pa[mt] = v ? A + (size_t)((id * D + ih) * D + iw) * CIN : Z;
        }
        fb = ((size_t)tap * nNtTot + N0t) * KC;
    };

    f16x8 fa[2][MT], fbh[2][NT], fbl[2][NT];
    auto load_frags = [&](int buf, int kc) {
        const int ko = kc * 32 + kq * 8;
        #pragma unroll
        for (int mt = 0; mt < MT; ++mt)
            fa[buf][mt] = *(const f16x8*)(pa[mt] + ko);
        #pragma unroll
        for (int nt = 0; nt < NT; ++nt) {
            const size_t fo = (fb + (size_t)nt * KC + kc) * 512 + lane * 8;
            fbh[buf][nt] = *(const f16x8*)(Bh + fo);
            fbl[buf][nt] = *(const f16x8*)(Bl + fo);
        }
    };

    set_tap(0);
    load_frags(0, 0);

    for (int tap = 0; tap < 27; ++tap) {
        #pragma unroll
        for (int kc = 0; kc < KC; ++kc) {
            const int cur = kc & 1, nxt = cur ^ 1;
            if (kc + 1 < KC) {
                load_frags(nxt, kc + 1);
            } else {
                set_tap(tap < 26 ? tap + 1 : 26);
                load_frags(nxt, 0);
            }
            #pragma unroll
            for (int mt = 0; mt < MT; ++mt)
            #pragma unroll
            for (int nt = 0; nt < NT; ++nt) {
                acc[mt][nt] = __builtin_amdgcn_mfma_f32_16x16x32_f16(fa[cur][mt], fbh[cur][nt], acc[mt][nt], 0, 0, 0);
                acc[mt][nt] = __builtin_amdgcn_mfma_f32_16x16x32_f16(fa[cur][mt], fbl[cur][nt], acc[mt][nt], 0, 0, 0);
            }
        }
    }

    #pragma unroll
    for (int mt = 0; mt < MT; ++mt) {
        const int vox0 = M0 + mt * 16 + kq * 4;
        #pragma unroll
        for (int nt = 0; nt < NT; ++nt) {
            const int co = (N0t + nt) * 16 + ml;
            #pragma unroll
            for (int r = 0; r < 4; ++r) {
                float v = acc[mt][nt][r];
                if (RELU) v = fmaxf(v, 0.f);
                Y[(size_t)(vox0 + r) * Cout + co] = f2h(v);
            }
        }
    }
}

// ---------- fp16 stride-2 deconv (parity-decomposed), A single, W hi/lo, 2-term -------
template<int CIN, int MT, int NT>
__global__ __launch_bounds__(64) void deconv_s2_f16(
    const u16* __restrict__ A, const u16* __restrict__ Bh, const u16* __restrict__ Bl,
    const float* __restrict__ bias, const u16* __restrict__ Z,
    u16* __restrict__ Y, int Din, int lD, int Cout, int nNtTot)
{
    constexpr int KC = CIN >> 5;
    const int Dout = 2 * Din;
    const int lane = threadIdx.x;
    const int ml = lane & 15, kq = lane >> 4;
    const int M0 = swz(blockIdx.x, gridDim.x) * (MT * 16);
    const int N0t = blockIdx.y * NT;
    const int par = blockIdx.z;
    const int rd = (par >> 2) & 1, rh = (par >> 1) & 1, rw = par & 1;

    int sw[MT], sh[MT], sd[MT];
    #pragma unroll
    for (int mt = 0; mt < MT; ++mt) {
        const int sv = M0 + mt * 16 + ml;
        sw[mt] = sv & (Din - 1); sh[mt] = (sv >> lD) & (Din - 1); sd[mt] = sv >> (2 * lD);
    }

    f32x4 acc[MT][NT];
    #pragma unroll
    for (int nt = 0; nt < NT; ++nt) {
        const float bv = bias[(N0t + nt) * 16 + ml];
        #pragma unroll
        for (int mt = 0; mt < MT; ++mt) acc[mt][nt] = (f32x4){bv, bv, bv, bv};
    }

    const int lw = rw ? 0 : 1, lh = rh ? 0 : 1, ld2 = rd ? 0 : 1;
    const int ntap = 1 << (lw + lh + ld2);

    const u16* pa[MT];
    size_t fb;
    auto set_tap = [&](int t) {
        const int tw_ = t & ((1 << lw) - 1);
        const int th_ = (t >> lw) & ((1 << lh) - 1);
        const int td_ = t >> (lw + lh);
        const int kd = rd ? 1 : (td_ ? 0 : 2);
        const int kh = rh ? 1 : (th_ ? 0 : 2);
        const int kw = rw ? 1 : (tw_ ? 0 : 2);
        const int dd = rd ? 0 : -td_, dh = rh ? 0 : -th_, dw = rw ? 0 : -tw_;
        const int tap = (kd * 3 + kh) * 3 + kw;
        #pragma unroll
        for (int mt = 0; mt < MT; ++mt) {
            const int id = sd[mt] + dd, ih = sh[mt] + dh, iw = sw[mt] + dw;
            const bool v = id >= 0 && ih >= 0 && iw >= 0;
            pa[mt] = v ? A + (size_t)((id * Din + ih) * Din + iw) * CIN : Z;
        }
        fb = ((size_t)tap * nNtTot + N0t) * KC;
    };

    f16x8 fa[2][MT], fbh[2][NT], fbl[2][NT];
    auto load_frags = [&](int buf, int kc) {
        const int ko = kc * 32 + kq * 8;
        #pragma unroll
        for (int mt = 0; mt < MT; ++mt)
            fa[buf][mt] = *(const f16x8*)(pa[mt] + ko);
        #pragma unroll
        for (int nt = 0; nt < NT; ++nt) {
            const size_t fo = (fb + (size_t)nt * KC + kc) * 512 + lane * 8;
            fbh[buf][nt] = *(const f16x8*)(Bh + fo);
            fbl[buf][nt] = *(const f16x8*)(Bl + fo);
        }
    };

    set_tap(0);
    load_frags(0, 0);

    for (int t = 0; t < ntap; ++t) {
        #pragma unroll
        for (int kc = 0; kc < KC; ++kc) {
            const int cur = kc & 1, nxt = cur ^ 1;
            if (kc + 1 < KC) {
                load_frags(nxt, kc + 1);
            } else {
                set_tap(t + 1 < ntap ? t + 1 : t);
                load_frags(nxt, 0);
            }
            #pragma unroll
            for (int mt = 0; mt < MT; ++mt)
            #pragma unroll
            for (int nt = 0; nt < NT; ++nt) {
                acc[mt][nt] = __builtin_amdgcn_mfma_f32_16x16x32_f16(fa[cur][mt], fbh[cur][nt], acc[mt][nt], 0, 0, 0);
                acc[mt][nt] = __builtin_amdgcn_mfma_f32_16x16x32_f16(fa[cur][mt], fbl[cur][nt], acc[mt][nt], 0, 0, 0);
            }
        }
    }

    #pragma unroll
    for (int mt = 0; mt < MT; ++mt) {
        #pragma unroll
        for (int r = 0; r < 4; ++r) {
            const int sv = M0 + mt * 16 + kq * 4 + r;
            const int svw = sv & (Din - 1), svh = (sv >> lD) & (Din - 1), svd = sv >> (2 * lD);
            const int od = 2 * svd + rd, oh = 2 * svh + rh, ow = 2 * svw + rw;
            const size_t yb = (size_t)((od * Dout + oh) * Dout + ow) * Cout;
            #pragma unroll
            for (int nt = 0; nt < NT; ++nt)
                Y[yb + (N0t + nt) * 16 + ml] = f2h(acc[mt][nt][r]);
        }
    }
}

// ---------- L3: fp16 stride-1, LDS stages TWO kc slices per phase (VST=72) ----------
template<int D, int R, bool RELU>
__global__ __launch_bounds__(256) void conv_s1_lds_f16(
    const u16* __restrict__ A, const u16* __restrict__ Bh, const u16* __restrict__ Bl,
    const float* __restrict__ bias, u16* __restrict__ Y)
{
    constexpr int SH  = R + 2;
    constexpr int SW  = D + 2;
    constexpr int VST = 72;               // 64 fp16 (two kc slices) + 8 pad — 16B-aligned
    __shared__ u16 sm[3 * SH * SW * VST]; // 58,752 B

    const int tid  = threadIdx.x;
    const int lane = tid & 63, widx = tid >> 6;
    const int ml = lane & 15, kq = lane >> 4;

    const int bpp = D / R;
    const int lb  = swz(blockIdx.x, gridDim.x);
    const int d   = lb / bpp;
    const int h0  = (lb % bpp) * R;
    const int N0  = widx * 2;

    f32x4 acc[4][2];
    #pragma unroll
    for (int nt = 0; nt < 2; ++nt) {
        const float bv = bias[(N0 + nt) * 16 + ml];
        #pragma unroll
        for (int mt = 0; mt < 4; ++mt) acc[mt][nt] = (f32x4){bv, bv, bv, bv};
    }

    // zero w-edge pad slots (slot 0 and SW-1), 8 chunks each, once
    for (int i = tid; i < 3 * SH * 2 * 8; i += 256) {
        const int slot = i >> 3, c8 = i & 7;
        const int side = slot & 1, rr = slot >> 1;
        const int dd = rr / SH, hh = rr % SH;
        *(f16x8*)(sm + ((dd * SH + hh) * SW + (side ? SW - 1 : 0)) * VST + c8 * 8) =
            (f16x8){0,0,0,0,0,0,0,0};
    }

    // B frags: [nt][kcl][h/l] current + next
    f16x8 cb[2][2][2], nb[2][2][2];
    auto loadB = [&](f16x8 (&dst)[2][2][2], int kcp, int tap) {
        #pragma unroll
        for (int nt = 0; nt < 2; ++nt)
        #pragma unroll
        for (int kcl = 0; kcl < 2; ++kcl) {
            const size_t fo = (((size_t)tap * 8 + N0 + nt) * 4 + kcp * 2 + kcl) * 512
                            + lane * 8;
            dst[nt][kcl][0] = *(const f16x8*)(Bh + fo);
            dst[nt][kcl][1] = *(const f16x8*)(Bl + fo);
        }
    };
    loadB(cb, 0, 0);

    for (int kcp = 0; kcp < 2; ++kcp) {           // 2 phases of 64 channels
        __syncthreads();
        // stage 3 x SH x D voxels x 8 chunks (64 fp16 = kc pair)
        constexpr int NCH = 3 * SH * D * 8;
        for (int i = tid; i < NCH; i += 256) {
            const int vox = i >> 3, c8 = i & 7;
            const int ww = vox % D;
            const int rr = vox / D;
            const int hh = rr % SH, dd = rr / SH;
            const int pd = d + dd - 1, ph = h0 + hh - 1;
            u16* dst = sm + ((dd * SH + hh) * SW + ww + 1) * VST + c8 * 8;
            if ((unsigned)pd < (unsigned)D && (unsigned)ph < (unsigned)D) {
                const size_t g = ((size_t)(pd * D + ph) * D + ww) * 128 + kcp * 64 + c8 * 8;
                *(f16x8*)dst = *(const f16x8*)(A + g);
            } else {
                *(f16x8*)dst = (f16x8){0,0,0,0,0,0,0,0};
            }
        }
        __syncthreads();

        for (int tap = 0; tap < 27; ++tap) {
            const int lin = kcp * 27 + tap + 1;
            if (lin < 54) loadB(nb, lin / 27, lin % 27);
            const int kd = tap / 9, kh = (tap % 9) / 3, kw = tap % 3;
            f16x8 fa[4][2];
            #pragma unroll
            for (int mt = 0; mt < 4; ++mt) {
                const int m = mt * 16 + ml;
                const int mh = m / D, mw = m % D;
                const u16* p = sm + (((kd * SH) + (mh + kh)) * SW + (mw + kw)) * VST;
                fa[mt][0] = *(const f16x8*)(p + kq * 8);
                fa[mt][1] = *(const f16x8*)(p + 32 + kq * 8);
            }
            #pragma unroll
            for (int mt = 0; mt < 4; ++mt)
            #pragma unroll
            for (int nt = 0; nt < 2; ++nt)
            #pragma unroll
            for (int kcl = 0; kcl < 2; ++kcl) {
                acc[mt][nt] = __builtin_amdgcn_mfma_f32_16x16x32_f16(fa[mt][kcl], cb[nt][kcl][0], acc[mt][nt], 0, 0, 0);
                acc[mt][nt] = __builtin_amdgcn_mfma_f32_16x16x32_f16(fa[mt][kcl], cb[nt][kcl][1], acc[mt][nt], 0, 0, 0);
            }
            #pragma unroll
            for (int nt = 0; nt < 2; ++nt)
            #pragma unroll
            for (int kcl = 0; kcl < 2; ++kcl) {
                cb[nt][kcl][0] = nb[nt][kcl][0];
                cb[nt][kcl][1] = nb[nt][kcl][1];
            }
        }
    }

    const size_t M0 = (size_t)(d * D + h0) * D;
    #pragma unroll
    for (int mt = 0; mt < 4; ++mt) {
        #pragma unroll
        for (int nt = 0; nt < 2; ++nt) {
            const int co = (N0 + nt) * 16 + ml;
            #pragma unroll
            for (int r = 0; r < 4; ++r) {
                float v = acc[mt][nt][r];
                if (RELU) v = fmaxf(v, 0.f);
                Y[(M0 + mt * 16 + kq * 4 + r) * 128 + co] = f2h(v);
            }
        }
    }
}

// ---------- L5: D=64, Cin=64 -> Cout=3 (N pad 16), both kc staged (VST=72) ----------
#define L5_VST 72
#define L5_RST (66 * L5_VST)
__global__ __launch_bounds__(256) void conv_c3_lds(
    const u16* __restrict__ A,
    const u16* __restrict__ Bh, const u16* __restrict__ Bl,
    const float* __restrict__ bias, float* __restrict__ out)
{
    __shared__ u16 sm[6 * L5_RST];        // 57,024 B

    const int tid  = threadIdx.x;
    const int lane = tid & 63, widx = tid >> 6;
    const int ml = lane & 15, kq = lane >> 4;

    const int lb = swz(blockIdx.x, gridDim.x);
    const int d  = lb >> 4;
    const int h0 = (lb & 15) * 4;

    const float bv = (ml < 3) ? bias[ml] : 0.f;
    f32x4 acc[4];
    #pragma unroll
    for (int mt = 0; mt < 4; ++mt) acc[mt] = (f32x4){bv, bv, bv, bv};

    f16x8 cb[2][2], nb[2][2];             // [kcl][h/l]
    auto loadB = [&](f16x8 (&dst)[2][2], int tap) {
        #pragma unroll
        for (int kcl = 0; kcl < 2; ++kcl) {
            const size_t fo = ((size_t)tap * 2 + kcl) * 512 + lane * 8;
            dst[kcl][0] = *(const f16x8*)(Bh + fo);
            dst[kcl][1] = *(const f16x8*)(Bl + fo);
        }
    };
    loadB(cb, 0);

    for (int kd = 0; kd < 3; ++kd) {      // 3 phases (both kc staged at once)
        const int pd = d + kd - 1;
        const bool vpd = (unsigned)pd < 64u;
        __syncthreads();
        // stage 6 rows x 64 vox x 8 chunks (64 fp16) = 3072 chunks
        #pragma unroll
        for (int i = 0; i < 12; ++i) {
            const int c = tid + 256 * i;
            const int r = c >> 9;
            const int rem = c & 511;
            const int vox = rem >> 3, c8 = rem & 7;
            const int hh = h0 - 1 + r;
            u16* dst = sm + r * L5_RST + (vox + 1) * L5_VST + c8 * 8;
            if (vpd && (unsigned)hh < 64u) {
                const size_t g = (size_t)((pd * 64 + hh) * 64 + vox) * 64 + c8 * 8;
                *(f16x8*)dst = *(const f16x8*)(A + g);
            } else {
                *(f16x8*)dst = (f16x8){0,0,0,0,0,0,0,0};
            }
        }
        if (tid < 96) {
            const int r = tid >> 4, side = (tid >> 3) & 1, c8 = tid & 7;
            *(f16x8*)(sm + r * L5_RST + (side ? 65 : 0) * L5_VST + c8 * 8) =
                (f16x8){0,0,0,0,0,0,0,0};
        }
        __syncthreads();

        #pragma unroll
        for (int t = 0; t < 9; ++t) {
            {
                int lin = kd * 9 + t + 1;
                if (lin > 26) lin = 26;
                loadB(nb, lin);
            }
            const int kh = t / 3, kw = t - kh * 3;
            const int slot = widx + kh;
            #pragma unroll
            for (int mt = 0; mt < 4; ++mt) {
                const u16* p = sm + slot * L5_RST + (mt * 16 + ml + kw) * L5_VST;
                const f16x8 a0 = *(const f16x8*)(p + kq * 8);
                const f16x8 a1 = *(const f16x8*)(p + 32 + kq * 8);
                acc[mt] = __builtin_amdgcn_mfma_f32_16x16x32_f16(a0, cb[0][0], acc[mt], 0, 0, 0);
                acc[mt] = __builtin_amdgcn_mfma_f32_16x16x32_f16(a0, cb[0][1], acc[mt], 0, 0, 0);
                acc[mt] = __builtin_amdgcn_mfma_f32_16x16x32_f16(a1, cb[1][0], acc[mt], 0, 0, 0);
                acc[mt] = __builtin_amdgcn_mfma_f32_16x16x32_f16(a1, cb[1][1], acc[mt], 0, 0, 0);
            }
            #pragma unroll
            for (int kcl = 0; kcl < 2; ++kcl) { cb[kcl][0] = nb[kcl][0]; cb[kcl][1] = nb[kcl][1]; }
        }
    }

    if (ml < 3) {
        const int h = h0 + widx;
        const size_t vb = (size_t)(d * 64 + h) * 64;
        #pragma unroll
        for (int mt = 0; mt < 4; ++mt)
        #pragma unroll
        for (int r = 0; r < 4; ++r)
            out[(vb + mt * 16 + kq * 4 + r) * 3 + ml] = acc[mt][r];
    }
}

extern "C" void kernel_launch(void* const* d_in, const int* in_sizes, int n_in,
                              void* d_out, int out_size, void* d_ws, size_t ws_size,
                              hipStream_t stream)
{
    const float* x   = (const float*)d_in[0];
    const float* w0  = (const float*)d_in[1];  const float* b0  = (const float*)d_in[2];
    const float* w00 = (const float*)d_in[3];  const float* b00 = (const float*)d_in[4];
    const float* w1  = (const float*)d_in[5];  const float* b1  = (const float*)d_in[6];
    const float* w10 = (const float*)d_in[7];  const float* b10 = (const float*)d_in[8];
    const float* w2  = (const float*)d_in[9];  const float* b2  = (const float*)d_in[10];
    const float* w20 = (const float*)d_in[11]; const float* b20 = (const float*)d_in[12];
    float* out = (float*)d_out;

    char* ws = (char*)d_ws;
    float* zf = (float*)ws;                      // 4 KB zero page
    u16*   Z  = (u16*)ws;
    u16* S4h = (u16*)(ws + 4096);                // durable packed weights (L4, L5)
    u16* S4l = S4h + 221184;
    u16* S5h = S4l + 221184;
    u16* S5l = S5h + 27648;
    u16* Qh  = (u16*)(ws + 1048576);             // fp16 activations (L1/L3 out)
    u16* Ql  = Qh + 4194304;
    u16* Ph  = (u16*)(ws + 17825792);            // fp16 activations (L0/L2/L4 out)
    u16* Pl  = Ph + 16777216;
    u16* S1h = (u16*)(ws + 60817408);            // transient packed weights (Pl tail)
    u16* S1l = S1h + 442368;
    u16* S2h = S1l + 442368;
    u16* S2l = S2h + 442368;
    u16* S3h = S2l + 442368;
    u16* S3l = S3h + 442368;
    u16* S0h = S3l + 442368;
    u16* S0l = S0h + 442368;
    u16* Xh  = S0l + 442368;
    u16* Xl  = Xh + 65536;

    pack_all<<<dim3(216, 7), 256, 0, stream>>>(x, zf, Xh, Xl,
        w0, w00, w1, w10, w2, w20,
        S0h, S0l, S1h, S1l, S2h, S2l, S3h, S3l, S4h, S4l, S5h, S5l);

    // L0: X(8^3x128) --s2 bf16 3-term--> P(16^3x128 fp16). Din=8, MT=2,NT=4.
    deconv_s2_bf16<128, 2, 4><<<dim3(16, 2, 8), 64, 0, stream>>>(
        Xh, Xl, S0h, S0l, b0, Z, Ph, 8, 3, 128, 8);

    // L1: P --s1+relu--> Q (D=16). fp16 2-term, MT=1,NT=2.
    conv_s1_f16<128, 1, 2, true><<<dim3(256, 4), 64, 0, stream>>>(
        Ph, S1h, S1l, b00, Z, Qh, 16, 4, 128, 8);

    // L2: Q --s2--> P (Din=16). fp16 2-term, MT=2,NT=4.
    deconv_s2_f16<128, 2, 4><<<dim3(128, 2, 8), 64, 0, stream>>>(
        Qh, S2h, S2l, b1, Z, Ph, 16, 4, 128, 8);

    // L3: P --s1+relu--> Q (D=32). fp16 LDS, 2 kc-pair phases, 512 blocks x 4 waves.
    conv_s1_lds_f16<32, 2, true><<<dim3(512), 256, 0, stream>>>(
        Ph, S3h, S3l, b10, Qh);

    // L4: Q --s2--> P (Din=32, Cout=64). fp16 2-term, MT=4,NT=4.
    deconv_s2_f16<128, 4, 4><<<dim3(512, 1, 8), 64, 0, stream>>>(
        Qh, S4h, S4l, b2, Z, Ph, 32, 5, 64, 4);

    // L5: P(fp16) --s1--> out. fp16 LDS, 3 kd phases (both kc staged), 1024 blocks.
    conv_c3_lds<<<dim3(1024), 256, 0, stream>>>(Ph, S5h, S5l, b20, out);
}

// Round 17
// 308.688 us; speedup vs baseline: 1.0234x; 1.0234x over previous
//
#include <hip/hip_runtime.h>

// Decoder via MFMA implicit GEMM, mixed-precision:
//   L0: bf16 hi/lo x bf16 hi/lo (3-term). L1-L5: fp16-single activations x fp16 hi/lo
//   weights (2-term). R14/R15 measured: fp16 internal edges add ZERO absmax error.
// conv_transpose SAME:
//   stride1: O[o] = sum_k W[k] X[o+k-1]
//   stride2, parity r: r==1 -> tap kd=1,id=i ; r==0 -> kd=2,id=i and kd=0,id=i-1  (o=2i+r)
// Weights DHWIO [tap][ci][co], activations NDHWC.
// MFMA layouts (verified): A[m=lane&15][k=(lane>>4)*8+j], B[n=lane&15][k=(lane>>4)*8+j],
// D: col=lane&15, row=(lane>>4)*4+reg. C/D layout dtype-independent.
// LDS rule (R10): voxel slot stride must be a multiple of 8 u16 (16B) or b128 ops split.
//
// Round17: keep R16's L3 (two-kc-slice LDS, 2 phases: 65->60.4us, MfmaUtil 41%), revert
// L5 to R15's light variant (VST=40, 6 phases, 2 B-frags/tap — R16's 4-wide B prefetch +
// doubled B register set regressed it). Per-kernel A/B discipline.

typedef __attribute__((ext_vector_type(8))) short bf16x8;
typedef __attribute__((ext_vector_type(8))) _Float16 f16x8;
typedef __attribute__((ext_vector_type(4))) float f32x4;
typedef unsigned short u16;

__device__ __forceinline__ u16 f2bf(float f) {
    unsigned u = __builtin_bit_cast(unsigned, f);
    u += 0x7fffu + ((u >> 16) & 1u);
    return (u16)(u >> 16);
}
__device__ __forceinline__ float bf2f(u16 h) {
    unsigned u = ((unsigned)h) << 16;
    return __builtin_bit_cast(float, u);
}
__device__ __forceinline__ void split_store(float v, u16* ph, u16* pl) {
    u16 h = f2bf(v);
    *ph = h;
    *pl = f2bf(v - bf2f(h));
}
__device__ __forceinline__ u16 f2h(float v) {
    return __builtin_bit_cast(u16, (_Float16)v);
}
__device__ __forceinline__ int swz(int bx, int G) { return (bx & 7) * (G >> 3) + (bx >> 3); }

// pack fp32 w[27][Cin][Cout] -> frags [tap][nt][kc][lane][8].
// Layer 0: bf16 hi/lo. Layers 1-5: fp16 hi/lo. y==6: split x bf16 hi/lo + zero page.
__global__ __launch_bounds__(256) void pack_all(
    const float* __restrict__ x, float* __restrict__ zf,
    u16* __restrict__ Xh, u16* __restrict__ Xl,
    const float* __restrict__ w0_, const float* __restrict__ w1_,
    const float* __restrict__ w2_, const float* __restrict__ w3_,
    const float* __restrict__ w4_, const float* __restrict__ w5_,
    u16* s0h, u16* s0l, u16* s1h, u16* s1l, u16* s2h, u16* s2l,
    u16* s3h, u16* s3l, u16* s4h, u16* s4l, u16* s5h, u16* s5l)
{
    if (blockIdx.y == 6) {
        if (blockIdx.x < 64) {
            const int i = (blockIdx.x * 256 + threadIdx.x) * 4;
            const float4 v = *(const float4*)(x + i);
            split_store(v.x, Xh + i,     Xl + i);
            split_store(v.y, Xh + i + 1, Xl + i + 1);
            split_store(v.z, Xh + i + 2, Xl + i + 2);
            split_store(v.w, Xh + i + 3, Xl + i + 3);
        } else if (blockIdx.x == 64) {
            ((float4*)zf)[threadIdx.x] = make_float4(0.f, 0.f, 0.f, 0.f);
        }
        return;
    }
    const float* w; u16 *bh, *bl; int Cin, Cout, nNt;
    switch (blockIdx.y) {
        case 0: w = w0_; bh = s0h; bl = s0l; Cin = 128; Cout = 128; nNt = 8; break;
        case 1: w = w1_; bh = s1h; bl = s1l; Cin = 128; Cout = 128; nNt = 8; break;
        case 2: w = w2_; bh = s2h; bl = s2l; Cin = 128; Cout = 128; nNt = 8; break;
        case 3: w = w3_; bh = s3h; bl = s3l; Cin = 128; Cout = 128; nNt = 8; break;
        case 4: w = w4_; bh = s4h; bl = s4l; Cin = 128; Cout = 64;  nNt = 4; break;
        default:w = w5_; bh = s5h; bl = s5l; Cin = 64;  Cout = 3;   nNt = 1; break;
    }
    const bool f16 = (blockIdx.y >= 1);
    const int KC = Cin >> 5;
    const int total = 27 * nNt * KC * 64;
    int t = blockIdx.x * 256 + threadIdx.x;
    if (t >= total) return;
    const int lane = t & 63;
    int r = t >> 6;
    const int kc = r % KC; r /= KC;
    const int nt = r % nNt; r /= nNt;
    const int tap = r;
    const int n  = nt * 16 + (lane & 15);
    const int k0 = kc * 32 + (lane >> 4) * 8;
    const size_t o = (size_t)t * 8;
    for (int j = 0; j < 8; ++j) {
        float v = (n < Cout) ? w[((size_t)tap * Cin + k0 + j) * Cout + n] : 0.f;
        if (f16) {
            const _Float16 h = (_Float16)v;
            bh[o + j] = __builtin_bit_cast(u16, h);
            bl[o + j] = f2h(v - (float)h);
        } else {
            const u16 h = f2bf(v);
            bh[o + j] = h;
            bl[o + j] = f2bf(v - bf2f(h));
        }
    }
}

// ---------- L0 only: stride-2 bf16 hi/lo 3-term, fp16-single output ----------
template<int CIN, int MT, int NT>
__global__ __launch_bounds__(64) void deconv_s2_bf16(
    const u16* __restrict__ Ah, const u16* __restrict__ Al,
    const u16* __restrict__ Bh, const u16* __restrict__ Bl,
    const float* __restrict__ bias, const u16* __restrict__ Z,
    u16* __restrict__ Y, int Din, int lD, int Cout, int nNtTot)
{
    constexpr int KC = CIN >> 5;
    const int Dout = 2 * Din;
    const int lane = threadIdx.x;
    const int ml = lane & 15, kq = lane >> 4;
    const int M0 = swz(blockIdx.x, gridDim.x) * (MT * 16);
    const int N0t = blockIdx.y * NT;
    const int par = blockIdx.z;
    const int rd = (par >> 2) & 1, rh = (par >> 1) & 1, rw = par & 1;

    int sw[MT], sh[MT], sd[MT];
    #pragma unroll
    for (int mt = 0; mt < MT; ++mt) {
        const int sv = M0 + mt * 16 + ml;
        sw[mt] = sv & (Din - 1); sh[mt] = (sv >> lD) & (Din - 1); sd[mt] = sv >> (2 * lD);
    }

    f32x4 acc[MT][NT];
    #pragma unroll
    for (int nt = 0; nt < NT; ++nt) {
        const float bv = bias[(N0t + nt) * 16 + ml];
        #pragma unroll
        for (int mt = 0; mt < MT; ++mt) acc[mt][nt] = (f32x4){bv, bv, bv, bv};
    }

    const int lw = rw ? 0 : 1, lh = rh ? 0 : 1, ld2 = rd ? 0 : 1;
    const int ntap = 1 << (lw + lh + ld2);

    const u16 *pah[MT], *pal[MT];
    size_t fb;
    auto set_tap = [&](int t) {
        const int tw_ = t & ((1 << lw) - 1);
        const int th_ = (t >> lw) & ((1 << lh) - 1);
        const int td_ = t >> (lw + lh);
        const int kd = rd ? 1 : (td_ ? 0 : 2);
        const int kh = rh ? 1 : (th_ ? 0 : 2);
        const int kw = rw ? 1 : (tw_ ? 0 : 2);
        const int dd = rd ? 0 : -td_, dh = rh ? 0 : -th_, dw = rw ? 0 : -tw_;
        const int tap = (kd * 3 + kh) * 3 + kw;
        #pragma unroll
        for (int mt = 0; mt < MT; ++mt) {
            const int id = sd[mt] + dd, ih = sh[mt] + dh, iw = sw[mt] + dw;
            const bool v = id >= 0 && ih >= 0 && iw >= 0;
            const size_t off = (size_t)((id * Din + ih) * Din + iw) * CIN;
            pah[mt] = v ? Ah + off : Z;
            pal[mt] = v ? Al + off : Z;
        }
        fb = ((size_t)tap * nNtTot + N0t) * KC;
    };

    bf16x8 fah[2][MT], fal[2][MT], fbh[2][NT], fbl[2][NT];
    auto load_frags = [&](int buf, int kc) {
        const int ko = kc * 32 + kq * 8;
        #pragma unroll
        for (int mt = 0; mt < MT; ++mt) {
            fah[buf][mt] = *(const bf16x8*)(pah[mt] + ko);
            fal[buf][mt] = *(const bf16x8*)(pal[mt] + ko);
        }
        #pragma unroll
        for (int nt = 0; nt < NT; ++nt) {
            const size_t fo = (fb + (size_t)nt * KC + kc) * 512 + lane * 8;
            fbh[buf][nt] = *(const bf16x8*)(Bh + fo);
            fbl[buf][nt] = *(const bf16x8*)(Bl + fo);
        }
    };

    set_tap(0);
    load_frags(0, 0);

    for (int t = 0; t < ntap; ++t) {
        #pragma unroll
        for (int kc = 0; kc < KC; ++kc) {
            const int cur = kc & 1, nxt = cur ^ 1;
            if (kc + 1 < KC) {
                load_frags(nxt, kc + 1);
            } else {
                set_tap(t + 1 < ntap ? t + 1 : t);
                load_frags(nxt, 0);
            }
            #pragma unroll
            for (int mt = 0; mt < MT; ++mt)
            #pragma unroll
            for (int nt = 0; nt < NT; ++nt) {
                acc[mt][nt] = __builtin_amdgcn_mfma_f32_16x16x32_bf16(fah[cur][mt], fbh[cur][nt], acc[mt][nt], 0, 0, 0);
                acc[mt][nt] = __builtin_amdgcn_mfma_f32_16x16x32_bf16(fah[cur][mt], fbl[cur][nt], acc[mt][nt], 0, 0, 0);
                acc[mt][nt] = __builtin_amdgcn_mfma_f32_16x16x32_bf16(fal[cur][mt], fbh[cur][nt], acc[mt][nt], 0, 0, 0);
            }
        }
    }

    #pragma unroll
    for (int mt = 0; mt < MT; ++mt) {
        #pragma unroll
        for (int r = 0; r < 4; ++r) {
            const int sv = M0 + mt * 16 + kq * 4 + r;
            const int svw = sv & (Din - 1), svh = (sv >> lD) & (Din - 1), svd = sv >> (2 * lD);
            const int od = 2 * svd + rd, oh = 2 * svh + rh, ow = 2 * svw + rw;
            const size_t yb = (size_t)((od * Dout + oh) * Dout + ow) * Cout;
            #pragma unroll
            for (int nt = 0; nt < NT; ++nt)
                Y[yb + (N0t + nt) * 16 + ml] = f2h(acc[mt][nt][r]);
        }
    }
}

// ---------- fp16 stride-1 conv: A single, W hi/lo, 2-term; fp16-single out ----------
template<int CIN, int MT, int NT, bool RELU>
__global__ __launch_bounds__(64) void conv_s1_f16(
    const u16* __restrict__ A, const u16* __restrict__ Bh, const u16* __restrict__ Bl,
    const float* __restrict__ bias, const u16* __restrict__ Z,
    u16* __restrict__ Y, int D, int lD, int Cout, int nNtTot)
{
    constexpr int KC = CIN >> 5;
    const int lane = threadIdx.x;
    const int ml = lane & 15, kq = lane >> 4;
    const int M0 = swz(blockIdx.x, gridDim.x) * (MT * 16);
    const int N0t = blockIdx.y * NT;

    int vw[MT], vh[MT], vd[MT];
    #pragma unroll
    for (int mt = 0; mt < MT; ++mt) {
        const int vox = M0 + mt * 16 + ml;
        vw[mt] = vox & (D - 1); vh[mt] = (vox >> lD) & (D - 1); vd[mt] = vox >> (2 * lD);
    }

    f32x4 acc[MT][NT];
    #pragma unroll
    for (int nt = 0; nt < NT; ++nt) {
        const float bv = bias[(N0t + nt) * 16 + ml];
        #pragma unroll
        for (int mt = 0; mt < MT; ++mt) acc[mt][nt] = (f32x4){bv, bv, bv, bv};
    }

    const u16* pa[MT];
    size_t fb;
    auto set_tap = [&](int tap) {
        const int kd = tap / 9, kh = (tap % 9) / 3, kw = tap % 3;
        #pragma unroll
        for (int mt = 0; mt < MT; ++mt) {
            const int id = vd[mt] + kd - 1, ih = vh[mt] + kh - 1, iw = vw[mt] + kw - 1;
            const bool v = (unsigned)id < (unsigned)D && (unsigned)ih < (unsigned)D &&
                           (unsigned)iw < (unsigned)D;
            pa[mt] = v ? A + (size_t)((id * D + ih) * D + iw) * CIN : Z;
        }
        fb = ((size_t)tap * nNtTot + N0t) * KC;
    };

    f16x8 fa[2][MT], fbh[2][NT], fbl[2][NT];
    auto load_frags = [&](int buf, int kc) {
        const int ko = kc * 32 + kq * 8;
        #pragma unroll
        for (int mt = 0; mt < MT; ++mt)
            fa[buf][mt] = *(const f16x8*)(pa[mt] + ko);
        #pragma unroll
        for (int nt = 0; nt < NT; ++nt) {
            const size_t fo = (fb + (size_t)nt * KC + kc) * 512 + lane * 8;
            fbh[buf][nt] = *(const f16x8*)(Bh + fo);
            fbl[buf][nt] = *(const f16x8*)(Bl + fo);
        }
    };

    set_tap(0);
    load_frags(0, 0);

    for (int tap = 0; tap < 27; ++tap) {
        #pragma unroll
        for (int kc = 0; kc < KC; ++kc) {
            const int cur = kc & 1, nxt = cur ^ 1;
            if (kc + 1 < KC) {
                load_frags(nxt, kc + 1);
            } else {
                set_tap(tap < 26 ? tap + 1 : 26);
                load_frags(nxt, 0);
            }
            #pragma unroll
            for (int mt = 0; mt < MT; ++mt)
            #pragma unroll
            for (int nt = 0; nt < NT; ++nt) {
                acc[mt][nt] = __builtin_amdgcn_mfma_f32_16x16x32_f16(fa[cur][mt], fbh[cur][nt], acc[mt][nt], 0, 0, 0);
                acc[mt][nt] = __builtin_amdgcn_mfma_f32_16x16x32_f16(fa[cur][mt], fbl[cur][nt], acc[mt][nt], 0, 0, 0);
            }
        }
    }

    #pragma unroll
    for (int mt = 0; mt < MT; ++mt) {
        const int vox0 = M0 + mt * 16 + kq * 4;
        #pragma unroll
        for (int nt = 0; nt < NT; ++nt) {
            const int co = (N0t + nt) * 16 + ml;
            #pragma unroll
            for (int r = 0; r < 4; ++r) {
                float v = acc[mt][nt][r];
                if (RELU) v = fmaxf(v, 0.f);
                Y[(size_t)(vox0 + r) * Cout + co] = f2h(v);
            }
        }
    }
}

// ---------- fp16 stride-2 deconv (parity-decomposed), A single, W hi/lo, 2-term -------
template<int CIN, int MT, int NT>
__global__ __launch_bounds__(64) void deconv_s2_f16(
    const u16* __restrict__ A, const u16* __restrict__ Bh, const u16* __restrict__ Bl,
    const float* __restrict__ bias, const u16* __restrict__ Z,
    u16* __restrict__ Y, int Din, int lD, int Cout, int nNtTot)
{
    constexpr int KC = CIN >> 5;
    const int Dout = 2 * Din;
    const int lane = threadIdx.x;
    const int ml = lane & 15, kq = lane >> 4;
    const int M0 = swz(blockIdx.x, gridDim.x) * (MT * 16);
    const int N0t = blockIdx.y * NT;
    const int par = blockIdx.z;
    const int rd = (par >> 2) & 1, rh = (par >> 1) & 1, rw = par & 1;

    int sw[MT], sh[MT], sd[MT];
    #pragma unroll
    for (int mt = 0; mt < MT; ++mt) {
        const int sv = M0 + mt * 16 + ml;
        sw[mt] = sv & (Din - 1); sh[mt] = (sv >> lD) & (Din - 1); sd[mt] = sv >> (2 * lD);
    }

    f32x4 acc[MT][NT];
    #pragma unroll
    for (int nt = 0; nt < NT; ++nt) {
        const float bv = bias[(N0t + nt) * 16 + ml];
        #pragma unroll
        for (int mt = 0; mt < MT; ++mt) acc[mt][nt] = (f32x4){bv, bv, bv, bv};
    }

    const int lw = rw ? 0 : 1, lh = rh ? 0 : 1, ld2 = rd ? 0 : 1;
    const int ntap = 1 << (lw + lh + ld2);

    const u16* pa[MT];
    size_t fb;
    auto set_tap = [&](int t) {
        const int tw_ = t & ((1 << lw) - 1);
        const int th_ = (t >> lw) & ((1 << lh) - 1);
        const int td_ = t >> (lw + lh);
        const int kd = rd ? 1 : (td_ ? 0 : 2);
        const int kh = rh ? 1 : (th_ ? 0 : 2);
        const int kw = rw ? 1 : (tw_ ? 0 : 2);
        const int dd = rd ? 0 : -td_, dh = rh ? 0 : -th_, dw = rw ? 0 : -tw_;
        const int tap = (kd * 3 + kh) * 3 + kw;
        #pragma unroll
        for (int mt = 0; mt < MT; ++mt) {
            const int id = sd[mt] + dd, ih = sh[mt] + dh, iw = sw[mt] + dw;
            const bool v = id >= 0 && ih >= 0 && iw >= 0;
            pa[mt] = v ? A + (size_t)((id * Din + ih) * Din + iw) * CIN : Z;
        }
        fb = ((size_t)tap * nNtTot + N0t) * KC;
    };

    f16x8 fa[2][MT], fbh[2][NT], fbl[2][NT];
    auto load_frags = [&](int buf, int kc) {
        const int ko = kc * 32 + kq * 8;
        #pragma unroll
        for (int mt = 0; mt < MT; ++mt)
            fa[buf][mt] = *(const f16x8*)(pa[mt] + ko);
        #pragma unroll
        for (int nt = 0; nt < NT; ++nt) {
            const size_t fo = (fb + (size_t)nt * KC + kc) * 512 + lane * 8;
            fbh[buf][nt] = *(const f16x8*)(Bh + fo);
            fbl[buf][nt] = *(const f16x8*)(Bl + fo);
        }
    };

    set_tap(0);
    load_frags(0, 0);

    for (int t = 0; t < ntap; ++t) {
        #pragma unroll
        for (int kc = 0; kc < KC; ++kc) {
            const int cur = kc & 1, nxt = cur ^ 1;
            if (kc + 1 < KC) {
                load_frags(nxt, kc + 1);
            } else {
                set_tap(t + 1 < ntap ? t + 1 : t);
                load_frags(nxt, 0);
            }
            #pragma unroll
            for (int mt = 0; mt < MT; ++mt)
            #pragma unroll
            for (int nt = 0; nt < NT; ++nt) {
                acc[mt][nt] = __builtin_amdgcn_mfma_f32_16x16x32_f16(fa[cur][mt], fbh[cur][nt], acc[mt][nt], 0, 0, 0);
                acc[mt][nt] = __builtin_amdgcn_mfma_f32_16x16x32_f16(fa[cur][mt], fbl[cur][nt], acc[mt][nt], 0, 0, 0);
            }
        }
    }

    #pragma unroll
    for (int mt = 0; mt < MT; ++mt) {
        #pragma unroll
        for (int r = 0; r < 4; ++r) {
            const int sv = M0 + mt * 16 + kq * 4 + r;
            const int svw = sv & (Din - 1), svh = (sv >> lD) & (Din - 1), svd = sv >> (2 * lD);
            const int od = 2 * svd + rd, oh = 2 * svh + rh, ow = 2 * svw + rw;
            const size_t yb = (size_t)((od * Dout + oh) * Dout + ow) * Cout;
            #pragma unroll
            for (int nt = 0; nt < NT; ++nt)
                Y[yb + (N0t + nt) * 16 + ml] = f2h(acc[mt][nt][r]);
        }
    }
}

// ---------- L3: fp16 stride-1, LDS stages TWO kc slices per phase (VST=72, R16) ------
template<int D, int R, bool RELU>
__global__ __launch_bounds__(256) void conv_s1_lds_f16(
    const u16* __restrict__ A, const u16* __restrict__ Bh, const u16* __restrict__ Bl,
    const float* __restrict__ bias, u16* __restrict__ Y)
{
    constexpr int SH  = R + 2;
    constexpr int SW  = D + 2;
    constexpr int VST = 72;               // 64 fp16 (two kc slices) + 8 pad — 16B-aligned
    __shared__ u16 sm[3 * SH * SW * VST]; // 58,752 B

    const int tid  = threadIdx.x;
    const int lane = tid & 63, widx = tid >> 6;
    const int ml = lane & 15, kq = lane >> 4;

    const int bpp = D / R;
    const int lb  = swz(blockIdx.x, gridDim.x);
    const int d   = lb / bpp;
    const int h0  = (lb % bpp) * R;
    const int N0  = widx * 2;

    f32x4 acc[4][2];
    #pragma unroll
    for (int nt = 0; nt < 2; ++nt) {
        const float bv = bias[(N0 + nt) * 16 + ml];
        #pragma unroll
        for (int mt = 0; mt < 4; ++mt) acc[mt][nt] = (f32x4){bv, bv, bv, bv};
    }

    for (int i = tid; i < 3 * SH * 2 * 8; i += 256) {
        const int slot = i >> 3, c8 = i & 7;
        const int side = slot & 1, rr = slot >> 1;
        const int dd = rr / SH, hh = rr % SH;
        *(f16x8*)(sm + ((dd * SH + hh) * SW + (side ? SW - 1 : 0)) * VST + c8 * 8) =
            (f16x8){0,0,0,0,0,0,0,0};
    }

    f16x8 cb[2][2][2], nb[2][2][2];       // [nt][kcl][h/l]
    auto loadB = [&](f16x8 (&dst)[2][2][2], int kcp, int tap) {
        #pragma unroll
        for (int nt = 0; nt < 2; ++nt)
        #pragma unroll
        for (int kcl = 0; kcl < 2; ++kcl) {
            const size_t fo = (((size_t)tap * 8 + N0 + nt) * 4 + kcp * 2 + kcl) * 512
                            + lane * 8;
            dst[nt][kcl][0] = *(const f16x8*)(Bh + fo);
            dst[nt][kcl][1] = *(const f16x8*)(Bl + fo);
        }
    };
    loadB(cb, 0, 0);

    for (int kcp = 0; kcp < 2; ++kcp) {           // 2 phases of 64 channels
        __syncthreads();
        constexpr int NCH = 3 * SH * D * 8;
        for (int i = tid; i < NCH; i += 256) {
            const int vox = i >> 3, c8 = i & 7;
            const int ww = vox % D;
            const int rr = vox / D;
            const int hh = rr % SH, dd = rr / SH;
            const int pd = d + dd - 1, ph = h0 + hh - 1;
            u16* dst = sm + ((dd * SH + hh) * SW + ww + 1) * VST + c8 * 8;
            if ((unsigned)pd < (unsigned)D && (unsigned)ph < (unsigned)D) {
                const size_t g = ((size_t)(pd * D + ph) * D + ww) * 128 + kcp * 64 + c8 * 8;
                *(f16x8*)dst = *(const f16x8*)(A + g);
            } else {
                *(f16x8*)dst = (f16x8){0,0,0,0,0,0,0,0};
            }
        }
        __syncthreads();

        for (int tap = 0; tap < 27; ++tap) {
            const int lin = kcp * 27 + tap + 1;
            if (lin < 54) loadB(nb, lin / 27, lin % 27);
            const int kd = tap / 9, kh = (tap % 9) / 3, kw = tap % 3;
            f16x8 fa[4][2];
            #pragma unroll
            for (int mt = 0; mt < 4; ++mt) {
                const int m = mt * 16 + ml;
                const int mh = m / D, mw = m % D;
                const u16* p = sm + (((kd * SH) + (mh + kh)) * SW + (mw + kw)) * VST;
                fa[mt][0] = *(const f16x8*)(p + kq * 8);
                fa[mt][1] = *(const f16x8*)(p + 32 + kq * 8);
            }
            #pragma unroll
            for (int mt = 0; mt < 4; ++mt)
            #pragma unroll
            for (int nt = 0; nt < 2; ++nt)
            #pragma unroll
            for (int kcl = 0; kcl < 2; ++kcl) {
                acc[mt][nt] = __builtin_amdgcn_mfma_f32_16x16x32_f16(fa[mt][kcl], cb[nt][kcl][0], acc[mt][nt], 0, 0, 0);
                acc[mt][nt] = __builtin_amdgcn_mfma_f32_16x16x32_f16(fa[mt][kcl], cb[nt][kcl][1], acc[mt][nt], 0, 0, 0);
            }
            #pragma unroll
            for (int nt = 0; nt < 2; ++nt)
            #pragma unroll
            for (int kcl = 0; kcl < 2; ++kcl) {
                cb[nt][kcl][0] = nb[nt][kcl][0];
                cb[nt][kcl][1] = nb[nt][kcl][1];
            }
        }
    }

    const size_t M0 = (size_t)(d * D + h0) * D;
    #pragma unroll
    for (int mt = 0; mt < 4; ++mt) {
        #pragma unroll
        for (int nt = 0; nt < 2; ++nt) {
            const int co = (N0 + nt) * 16 + ml;
            #pragma unroll
            for (int r = 0; r < 4; ++r) {
                float v = acc[mt][nt][r];
                if (RELU) v = fmaxf(v, 0.f);
                Y[(M0 + mt * 16 + kq * 4 + r) * 128 + co] = f2h(v);
            }
        }
    }
}

// ---------- L5: D=64, Cin=64 -> Cout=3 (N pad 16), fp16 LDS (R15, VST=40) ----------
#define L5_VST 40
#define L5_RST (66 * L5_VST)
__global__ __launch_bounds__(256) void conv_c3_lds(
    const u16* __restrict__ A,
    const u16* __restrict__ Bh, const u16* __restrict__ Bl,
    const float* __restrict__ bias, float* __restrict__ out)
{
    __shared__ u16 sm[6 * L5_RST];

    const int tid  = threadIdx.x;
    const int lane = tid & 63, widx = tid >> 6;
    const int ml = lane & 15, kq = lane >> 4;

    const int lb = swz(blockIdx.x, gridDim.x);
    const int d  = lb >> 4;
    const int h0 = (lb & 15) * 4;

    const float bv = (ml < 3) ? bias[ml] : 0.f;
    f32x4 acc[4];
    #pragma unroll
    for (int mt = 0; mt < 4; ++mt) acc[mt] = (f32x4){bv, bv, bv, bv};

    f16x8 cbh, cbl, nbh, nbl;
    auto loadB = [&](f16x8& dh, f16x8& dl, int tap, int kc) {
        const size_t fo = ((size_t)tap * 2 + kc) * 512 + lane * 8;
        dh = *(const f16x8*)(Bh + fo);
        dl = *(const f16x8*)(Bl + fo);
    };
    loadB(cbh, cbl, 0, 0);

    for (int kd = 0; kd < 3; ++kd) {
        const int pd = d + kd - 1;
        const bool vpd = (unsigned)pd < 64u;
        for (int kc = 0; kc < 2; ++kc) {
            __syncthreads();
            #pragma unroll
            for (int i = 0; i < 6; ++i) {
                const int c = tid + 256 * i;
                const int r = c >> 8;
                const int rem = c & 255;
                const int vox = rem >> 2, c8 = rem & 3;
                const int hh = h0 - 1 + r;
                u16* dst = sm + r * L5_RST + (vox + 1) * L5_VST + c8 * 8;
                if (vpd && (unsigned)hh < 64u) {
                    const size_t g = (size_t)((pd * 64 + hh) * 64 + vox) * 64
                                   + kc * 32 + c8 * 8;
                    *(f16x8*)dst = *(const f16x8*)(A + g);
                } else {
                    *(f16x8*)dst = (f16x8){0,0,0,0,0,0,0,0};
                }
            }
            if (tid < 48) {
                const int r = tid >> 3, side = (tid >> 2) & 1, c8 = tid & 3;
                *(f16x8*)(sm + r * L5_RST + (side ? 65 : 0) * L5_VST + c8 * 8) =
                    (f16x8){0,0,0,0,0,0,0,0};
            }
            __syncthreads();

            #pragma unroll
            for (int t = 0; t < 9; ++t) {
                {
                    int lin = (kd * 2 + kc) * 9 + t + 1;
                    if (lin > 53) lin = 53;
                    const int Pn = lin / 9, tn = lin - Pn * 9;
                    loadB(nbh, nbl, (Pn >> 1) * 9 + tn, Pn & 1);
                }
                const int kh = t / 3, kw = t - kh * 3;
                const int slot = widx + kh;
                #pragma unroll
                for (int mt = 0; mt < 4; ++mt) {
                    const u16* p = sm + slot * L5_RST + (mt * 16 + ml + kw) * L5_VST;
                    const f16x8 af = *(const f16x8*)(p + kq * 8);
                    acc[mt] = __builtin_amdgcn_mfma_f32_16x16x32_f16(af, cbh, acc[mt], 0, 0, 0);
                    acc[mt] = __builtin_amdgcn_mfma_f32_16x16x32_f16(af, cbl, acc[mt], 0, 0, 0);
                }
                cbh = nbh; cbl = nbl;
            }
        }
    }

    if (ml < 3) {
        const int h = h0 + widx;
        const size_t vb = (size_t)(d * 64 + h) * 64;
        #pragma unroll
        for (int mt = 0; mt < 4; ++mt)
        #pragma unroll
        for (int r = 0; r < 4; ++r)
            out[(vb + mt * 16 + kq * 4 + r) * 3 + ml] = acc[mt][r];
    }
}

extern "C" void kernel_launch(void* const* d_in, const int* in_sizes, int n_in,
                              void* d_out, int out_size, void* d_ws, size_t ws_size,
                              hipStream_t stream)
{
    const float* x   = (const float*)d_in[0];
    const float* w0  = (const float*)d_in[1];  const float* b0  = (const float*)d_in[2];
    const float* w00 = (const float*)d_in[3];  const float* b00 = (const float*)d_in[4];
    const float* w1  = (const float*)d_in[5];  const float* b1  = (const float*)d_in[6];
    const float* w10 = (const float*)d_in[7];  const float* b10 = (const float*)d_in[8];
    const float* w2  = (const float*)d_in[9];  const float* b2  = (const float*)d_in[10];
    const float* w20 = (const float*)d_in[11]; const float* b20 = (const float*)d_in[12];
    float* out = (float*)d_out;

    char* ws = (char*)d_ws;
    float* zf = (float*)ws;                      // 4 KB zero page
    u16*   Z  = (u16*)ws;
    u16* S4h = (u16*)(ws + 4096);                // durable packed weights (L4, L5)
    u16* S4l = S4h + 221184;
    u16* S5h = S4l + 221184;
    u16* S5l = S5h + 27648;
    u16* Qh  = (u16*)(ws + 1048576);             // fp16 activations (L1/L3 out)
    u16* Ql  = Qh + 4194304;
    u16* Ph  = (u16*)(ws + 17825792);            // fp16 activations (L0/L2/L4 out)
    u16* Pl  = Ph + 16777216;
    u16* S1h = (u16*)(ws + 60817408);            // transient packed weights (Pl tail)
    u16* S1l = S1h + 442368;
    u16* S2h = S1l + 442368;
    u16* S2l = S2h + 442368;
    u16* S3h = S2l + 442368;
    u16* S3l = S3h + 442368;
    u16* S0h = S3l + 442368;
    u16* S0l = S0h + 442368;
    u16* Xh  = S0l + 442368;
    u16* Xl  = Xh + 65536;

    pack_all<<<dim3(216, 7), 256, 0, stream>>>(x, zf, Xh, Xl,
        w0, w00, w1, w10, w2, w20,
        S0h, S0l, S1h, S1l, S2h, S2l, S3h, S3l, S4h, S4l, S5h, S5l);

    // L0: X(8^3x128) --s2 bf16 3-term--> P(16^3x128 fp16). Din=8, MT=2,NT=4.
    deconv_s2_bf16<128, 2, 4><<<dim3(16, 2, 8), 64, 0, stream>>>(
        Xh, Xl, S0h, S0l, b0, Z, Ph, 8, 3, 128, 8);

    // L1: P --s1+relu--> Q (D=16). fp16 2-term, MT=1,NT=2.
    conv_s1_f16<128, 1, 2, true><<<dim3(256, 4), 64, 0, stream>>>(
        Ph, S1h, S1l, b00, Z, Qh, 16, 4, 128, 8);

    // L2: Q --s2--> P (Din=16). fp16 2-term, MT=2,NT=4.
    deconv_s2_f16<128, 2, 4><<<dim3(128, 2, 8), 64, 0, stream>>>(
        Qh, S2h, S2l, b1, Z, Ph, 16, 4, 128, 8);

    // L3: P --s1+relu--> Q (D=32). fp16 LDS, 2 kc-pair phases (R16 winner), 512 blocks.
    conv_s1_lds_f16<32, 2, true><<<dim3(512), 256, 0, stream>>>(
        Ph, S3h, S3l, b10, Qh);

    // L4: Q --s2--> P (Din=32, Cout=64). fp16 2-term, MT=4,NT=4.
    deconv_s2_f16<128, 4, 4><<<dim3(512, 1, 8), 64, 0, stream>>>(
        Qh, S4h, S4l, b2, Z, Ph, 32, 5, 64, 4);

    // L5: P(fp16) --s1--> out. fp16 LDS, 6 light phases (R15 winner), 1024 blocks.
    conv_c3_lds<<<dim3(1024), 256, 0, stream>>>(Ph, S5h, S5l, b20, out);
}